// Round 1
// baseline (283.304 us; speedup 1.0000x reference)
//
#include <hip/hip_runtime.h>

#define DIM 512
#define B_  64
#define L_  2048

typedef unsigned short u16;
typedef float f32x4 __attribute__((ext_vector_type(4)));
typedef short s16x8 __attribute__((ext_vector_type(8)));
typedef short s16x4 __attribute__((ext_vector_type(4)));

__device__ __forceinline__ u16 f2bf(float f) {
  union { float f; unsigned u; } x{f};
  unsigned r = x.u + 0x7FFFu + ((x.u >> 16) & 1u);
  return (u16)(r >> 16);
}

__device__ __forceinline__ float tanh_fast(float x) {
  float e2 = __expf(2.0f * x);
  return 1.0f - 2.0f / (e2 + 1.0f);
}

// ---------- prep: q = query @ Wq^T + bq ; Wr -> bf16 ----------
__global__ __launch_bounds__(256) void prep_kernel(
    const float* __restrict__ query, const float* __restrict__ Wq,
    const float* __restrict__ bq, const float* __restrict__ Wr,
    float* __restrict__ q_out, u16* __restrict__ Wrb) {
  const int blk = blockIdx.x;
  const int tid = threadIdx.x;
  if (blk < 64) {
    __shared__ float qs[DIM];
    for (int i = tid; i < DIM; i += 256) qs[i] = query[blk * DIM + i];
    __syncthreads();
    for (int o = tid; o < DIM; o += 256) {
      const float* w = Wq + o * DIM;
      float acc = 0.f;
      for (int k = 0; k < DIM; k += 4) {
        f32x4 a = *(const f32x4*)&qs[k];
        f32x4 b = *(const f32x4*)&w[k];
        acc += a.x * b.x + a.y * b.y + a.z * b.z + a.w * b.w;
      }
      q_out[blk * DIM + o] = acc + bq[o];
    }
  } else {
    const int c = blk - 64;
    const int base = c * 4096 + tid * 16;
#pragma unroll
    for (int i = 0; i < 4; ++i) {
      f32x4 a = *(const f32x4*)&Wr[base + i * 4];
      s16x4 o4;
      o4.x = (short)f2bf(a.x); o4.y = (short)f2bf(a.y);
      o4.z = (short)f2bf(a.z); o4.w = (short)f2bf(a.w);
      *(s16x4*)&Wrb[base + i * 4] = o4;
    }
  }
}

// ---------- main fused GEMM+epilogue ----------
// grid: (16 l-tiles, 4 o-tiles, 64 b) ; block 256 = 4 waves (2x2 of 64x64)
__global__ __launch_bounds__(256) void attn_main(
    const float* __restrict__ ref, const u16* __restrict__ Wrb,
    const float* __restrict__ q, const float* __restrict__ br,
    const float* __restrict__ v, float* __restrict__ e_out,
    float* __restrict__ upart) {
  const int lt = blockIdx.x, ot = blockIdx.y, b = blockIdx.z;
  const int l0 = lt * 128, o0 = ot * 128;
  const int tid = threadIdx.x;
  const int lane = tid & 63;
  const int wid = tid >> 6;
  const int wr = wid >> 1, wc = wid & 1;

  __shared__ __align__(16) u16 As[2][128][40];  // [o][k] bf16, +8 pad
  __shared__ __align__(16) u16 Bs[2][128][40];  // [l][k] bf16, +8 pad
  __shared__ __align__(16) float qpb_s[128];
  __shared__ __align__(16) float br_s[128];
  __shared__ __align__(16) float v_s[128];
  __shared__ __align__(16) float u_lds[2][128];

  if (tid < 128) {
    const int o = o0 + tid;
    const float brv = br[o];
    br_s[tid] = brv;
    qpb_s[tid] = q[b * DIM + o] + brv;  // tanh arg = acc + (q+br)
    v_s[tid] = v[o];
  }

  const size_t ref_bb = (size_t)b * DIM;

  f32x4 acc[4][4];
#pragma unroll
  for (int i = 0; i < 4; ++i)
#pragma unroll
    for (int j = 0; j < 4; ++j) acc[i][j] = (f32x4){0.f, 0.f, 0.f, 0.f};

  // prologue: stage k-tile 0 into buffer 0
  {
#pragma unroll
    for (int i = 0; i < 4; ++i) {
      const int idx = tid + i * 256, row = idx >> 3, f4 = idx & 7;
      f32x4 a = *(const f32x4*)&ref[(size_t)(l0 + row) * (B_ * DIM) + ref_bb + f4 * 4];
      s16x4 o4;
      o4.x = (short)f2bf(a.x); o4.y = (short)f2bf(a.y);
      o4.z = (short)f2bf(a.z); o4.w = (short)f2bf(a.w);
      *(s16x4*)&Bs[0][row][f4 * 4] = o4;
    }
#pragma unroll
    for (int i = 0; i < 2; ++i) {
      const int idx = tid + i * 256, row = idx >> 2, q4 = idx & 3;
      s16x8 a = *(const s16x8*)&Wrb[(o0 + row) * DIM + q4 * 8];
      *(s16x8*)&As[0][row][q4 * 8] = a;
    }
  }
  __syncthreads();

  const int rr = lane & 15;
  const int kg = (lane >> 4) * 8;
  int cur = 0;

  for (int t = 0; t < 16; ++t) {
    f32x4 bl[4];
    s16x8 al[2];
    const int ktn = (t + 1) * 32;
    if (t < 15) {  // issue next-tile global loads early (hide under MFMA)
#pragma unroll
      for (int i = 0; i < 4; ++i) {
        const int idx = tid + i * 256, row = idx >> 3, f4 = idx & 7;
        bl[i] = *(const f32x4*)&ref[(size_t)(l0 + row) * (B_ * DIM) + ref_bb + ktn + f4 * 4];
      }
#pragma unroll
      for (int i = 0; i < 2; ++i) {
        const int idx = tid + i * 256, row = idx >> 2, q4 = idx & 3;
        al[i] = *(const s16x8*)&Wrb[(o0 + row) * DIM + ktn + q4 * 8];
      }
    }
    // compute current k-tile
    s16x8 af[4], bf[4];
#pragma unroll
    for (int f = 0; f < 4; ++f)
      af[f] = *(const s16x8*)&As[cur][wr * 64 + f * 16 + rr][kg];
#pragma unroll
    for (int f = 0; f < 4; ++f)
      bf[f] = *(const s16x8*)&Bs[cur][wc * 64 + f * 16 + rr][kg];
#pragma unroll
    for (int fm = 0; fm < 4; ++fm)
#pragma unroll
      for (int fn = 0; fn < 4; ++fn)
        acc[fm][fn] = __builtin_amdgcn_mfma_f32_16x16x32_bf16(af[fm], bf[fn], acc[fm][fn], 0, 0, 0);
    __syncthreads();
    if (t < 15) {  // convert + write next tile into other buffer
#pragma unroll
      for (int i = 0; i < 4; ++i) {
        const int idx = tid + i * 256, row = idx >> 3, f4 = idx & 7;
        f32x4 a = bl[i];
        s16x4 o4;
        o4.x = (short)f2bf(a.x); o4.y = (short)f2bf(a.y);
        o4.z = (short)f2bf(a.z); o4.w = (short)f2bf(a.w);
        *(s16x4*)&Bs[cur ^ 1][row][f4 * 4] = o4;
      }
#pragma unroll
      for (int i = 0; i < 2; ++i) {
        const int idx = tid + i * 256, row = idx >> 2, q4 = idx & 3;
        *(s16x8*)&As[cur ^ 1][row][q4 * 8] = al[i];
      }
    }
    __syncthreads();
    cur ^= 1;
  }

  // epilogue: e = acc + br ; u += v * tanh(acc + q + br)
  const int rg = lane >> 4;
  float usum[4] = {0.f, 0.f, 0.f, 0.f};
#pragma unroll
  for (int fm = 0; fm < 4; ++fm) {
    const int ob = wr * 64 + fm * 16 + rg * 4;
    f32x4 brv = *(const f32x4*)&br_s[ob];
    f32x4 qpv = *(const f32x4*)&qpb_s[ob];
    f32x4 vv  = *(const f32x4*)&v_s[ob];
#pragma unroll
    for (int fn = 0; fn < 4; ++fn) {
      const int l = l0 + wc * 64 + fn * 16 + rr;
      const size_t ebase = ((size_t)(b * DIM + o0 + ob)) * L_ + l;
      f32x4 a = acc[fm][fn];
#pragma unroll
      for (int r = 0; r < 4; ++r) {
        float ev = a[r] + brv[r];
        __builtin_nontemporal_store(ev, &e_out[ebase + (size_t)r * L_]);
        usum[fn] += vv[r] * tanh_fast(a[r] + qpv[r]);
      }
    }
  }
#pragma unroll
  for (int fn = 0; fn < 4; ++fn) {
    float s = usum[fn];
    s += __shfl_xor(s, 16);
    s += __shfl_xor(s, 32);
    usum[fn] = s;
  }
  if (lane < 16) {
#pragma unroll
    for (int fn = 0; fn < 4; ++fn)
      u_lds[wr][wc * 64 + fn * 16 + lane] = usum[fn];
  }
  __syncthreads();
  if (tid < 128) {
    const float s = u_lds[0][tid] + u_lds[1][tid];
    upart[(size_t)(ot * 64 + b) * L_ + l0 + tid] = s;
  }
}

// ---------- reduce 4 o-tile partials -> logits ----------
__global__ __launch_bounds__(256) void ured_kernel(
    const float* __restrict__ up, float* __restrict__ out) {
  const int idx = blockIdx.x * 256 + threadIdx.x;
  out[idx] = up[idx] + up[idx + 131072] + up[idx + 262144] + up[idx + 393216];
}

extern "C" void kernel_launch(void* const* d_in, const int* in_sizes, int n_in,
                              void* d_out, int out_size, void* d_ws, size_t ws_size,
                              hipStream_t stream) {
  const float* query = (const float*)d_in[0];
  const float* ref   = (const float*)d_in[1];
  const float* Wq    = (const float*)d_in[2];
  const float* bq    = (const float*)d_in[3];
  const float* Wr    = (const float*)d_in[4];
  const float* br    = (const float*)d_in[5];
  const float* v     = (const float*)d_in[6];

  float* e_out  = (float*)d_out;
  float* logits = e_out + (size_t)B_ * DIM * L_;  // 67108864

  char* ws = (char*)d_ws;
  u16*   Wrb   = (u16*)ws;                          // 512 KB
  float* q     = (float*)(ws + 524288);             // 128 KB
  float* upart = (float*)(ws + 524288 + 131072);    // 2 MB

  prep_kernel<<<128, 256, 0, stream>>>(query, Wq, bq, Wr, q, Wrb);
  attn_main<<<dim3(16, 4, 64), 256, 0, stream>>>(ref, Wrb, q, br, v, e_out, upart);
  ured_kernel<<<512, 256, 0, stream>>>(upart, logits);
}

// Round 3
// 262.367 us; speedup vs baseline: 1.0798x; 1.0798x over previous
//
#include <hip/hip_runtime.h>

#define DIM 512
#define B_  64
#define L_  2048

typedef unsigned short u16;
typedef float f32x4 __attribute__((ext_vector_type(4)));
typedef short s16x8 __attribute__((ext_vector_type(8)));
typedef short s16x4 __attribute__((ext_vector_type(4)));

__device__ __forceinline__ u16 f2bf(float f) {
  union { float f; unsigned u; } x{f};
  unsigned r = x.u + 0x7FFFu + ((x.u >> 16) & 1u);
  return (u16)(r >> 16);
}

__device__ __forceinline__ float tanh_fast(float x) {
  float e2 = __expf(2.0f * x);
  return 1.0f - 2.0f / (e2 + 1.0f);
}

// ---------- prep: q = query @ Wq^T + bq ; Wr -> bf16 ----------
__global__ __launch_bounds__(256) void prep_kernel(
    const float* __restrict__ query, const float* __restrict__ Wq,
    const float* __restrict__ bq, const float* __restrict__ Wr,
    float* __restrict__ q_out, u16* __restrict__ Wrb) {
  const int blk = blockIdx.x;
  const int tid = threadIdx.x;
  if (blk < 64) {
    __shared__ float qs[DIM];
    for (int i = tid; i < DIM; i += 256) qs[i] = query[blk * DIM + i];
    __syncthreads();
    for (int o = tid; o < DIM; o += 256) {
      const float* w = Wq + o * DIM;
      float acc = 0.f;
      for (int k = 0; k < DIM; k += 4) {
        f32x4 a = *(const f32x4*)&qs[k];
        f32x4 b = *(const f32x4*)&w[k];
        acc += a.x * b.x + a.y * b.y + a.z * b.z + a.w * b.w;
      }
      q_out[blk * DIM + o] = acc + bq[o];
    }
  } else {
    const int c = blk - 64;
    const int base = c * 4096 + tid * 16;
#pragma unroll
    for (int i = 0; i < 4; ++i) {
      f32x4 a = *(const f32x4*)&Wr[base + i * 4];
      s16x4 o4;
      o4.x = (short)f2bf(a.x); o4.y = (short)f2bf(a.y);
      o4.z = (short)f2bf(a.z); o4.w = (short)f2bf(a.w);
      *(s16x4*)&Wrb[base + i * 4] = o4;
    }
  }
}

// ---------- main: panel-resident fused GEMM + epilogue ----------
// grid (16 l-tiles, 64 b); block 512 = 8 waves (wr: 2 o-split x wc: 4 l-split)
// Bs = whole 128l x 512k ref panel (bf16, +8 pad). As = dbuf 32k-slice of Wr,
// transposed layout [kc][o][8] with o^=(kc<<1) xor; reg-staged (no glds).
__global__ __launch_bounds__(512, 1) void attn_main(
    const float* __restrict__ ref, const u16* __restrict__ Wrb,
    const float* __restrict__ q, const float* __restrict__ br,
    const float* __restrict__ v, float* __restrict__ e_out,
    float* __restrict__ logits) {
  __shared__ u16 As[2][4][128][8];    // 16 KB
  __shared__ u16 Bs[128][520];        // 130 KB
  __shared__ float u_lds[2][128];

  const int lt = blockIdx.x, b = blockIdx.y;
  const int l0 = lt * 128;
  const int tid = threadIdx.x;
  const int lane = tid & 63;
  const int w = tid >> 6;
  const int wr = w >> 2, wc = w & 3;
  const int rr = lane & 15, kg = lane >> 4;

  // A-staging coords: thread fills physical slot (skc, soP); logical o = soP^(skc<<1)
  const int skc = tid >> 7;
  const int soP = tid & 127;
  const int soL = soP ^ (skc << 1);

  // ---- prologue ----
  s16x8 a0 = *(const s16x8*)&Wrb[(size_t)soL * DIM + skc * 8];  // ot=0, t=0
#pragma unroll
  for (int g = 0; g < 4; ++g) {
    f32x4 r[8];
#pragma unroll
    for (int i = 0; i < 8; ++i) {
      int flat = g * 4096 + i * 512 + tid;
      int row = flat >> 7, c = flat & 127;
      r[i] = *(const f32x4*)&ref[(size_t)(l0 + row) * (B_ * DIM) + (size_t)b * DIM + c * 4];
    }
#pragma unroll
    for (int i = 0; i < 8; ++i) {
      int flat = g * 4096 + i * 512 + tid;
      int row = flat >> 7, c = flat & 127;
      s16x4 o4;
      o4.x = (short)f2bf(r[i].x); o4.y = (short)f2bf(r[i].y);
      o4.z = (short)f2bf(r[i].z); o4.w = (short)f2bf(r[i].w);
      *(s16x4*)&Bs[row][c * 4] = o4;
    }
  }
  *(s16x8*)&As[0][skc][soP][0] = a0;
  __syncthreads();

  f32x4 accT[2][4];
#pragma unroll
  for (int fn = 0; fn < 2; ++fn)
#pragma unroll
    for (int fm = 0; fm < 4; ++fm) accT[fn][fm] = (f32x4){0.f, 0.f, 0.f, 0.f};

  for (int s = 0; s < 64; ++s) {
    const int cur = s & 1, t = s & 15, ot = s >> 4;
    s16x8 anx;
    if (s < 63) {  // issue next A-tile global load early (L2-hot Wrb)
      const int sn = s + 1, otn = sn >> 4, tn = sn & 15;
      anx = *(const s16x8*)&Wrb[(size_t)((otn << 7) + soL) * DIM + tn * 32 + skc * 8];
    }
    s16x8 af[4], bf[2];
#pragma unroll
    for (int fm = 0; fm < 4; ++fm) {
      int row = wr * 64 + fm * 16 + rr;
      af[fm] = *(const s16x8*)&As[cur][kg][row ^ (kg << 1)][0];
    }
#pragma unroll
    for (int fn = 0; fn < 2; ++fn)
      bf[fn] = *(const s16x8*)&Bs[wc * 32 + fn * 16 + rr][t * 32 + kg * 8];
#pragma unroll
    for (int fn = 0; fn < 2; ++fn)
#pragma unroll
      for (int fm = 0; fm < 4; ++fm)
        accT[fn][fm] = __builtin_amdgcn_mfma_f32_16x16x32_bf16(bf[fn], af[fm], accT[fn][fm], 0, 0, 0);
    if (s < 63) *(s16x8*)&As[cur ^ 1][skc][soP][0] = anx;
    __syncthreads();

    if (t == 15) {  // epilogue for this o-tile; acc rows = l (swapped operands)
      const int ob = (ot << 7) + wr * 64;
      float bb[4], vv[4], qq[4];
#pragma unroll
      for (int fm = 0; fm < 4; ++fm) {
        int o = ob + fm * 16 + rr;
        bb[fm] = br[o]; vv[fm] = v[o]; qq[fm] = q[b * DIM + o] + bb[fm];
      }
#pragma unroll
      for (int fn = 0; fn < 2; ++fn) {
        f32x4 us = (f32x4){0.f, 0.f, 0.f, 0.f};
        const int lb = l0 + wc * 32 + fn * 16 + kg * 4;
#pragma unroll
        for (int fm = 0; fm < 4; ++fm) {
          int o = ob + fm * 16 + rr;
          f32x4 a = accT[fn][fm];
          f32x4 ev = a + bb[fm];
          __builtin_nontemporal_store(ev, (f32x4*)&e_out[((size_t)(b * DIM + o)) * L_ + lb]);
          f32x4 th;
          th.x = tanh_fast(a.x + qq[fm]);
          th.y = tanh_fast(a.y + qq[fm]);
          th.z = tanh_fast(a.z + qq[fm]);
          th.w = tanh_fast(a.w + qq[fm]);
          us += vv[fm] * th;
          accT[fn][fm] = (f32x4){0.f, 0.f, 0.f, 0.f};
        }
#pragma unroll
        for (int msk = 1; msk <= 8; msk <<= 1) {
          us.x += __shfl_xor(us.x, msk);
          us.y += __shfl_xor(us.y, msk);
          us.z += __shfl_xor(us.z, msk);
          us.w += __shfl_xor(us.w, msk);
        }
        if (rr == 0) {
          float* up = &u_lds[wr][wc * 32 + fn * 16 + kg * 4];
          if (ot == 0) {
            *(f32x4*)up = us;
          } else {
            f32x4 old = *(f32x4*)up;
            *(f32x4*)up = old + us;
          }
        }
      }
    }
  }
  __syncthreads();
  if (tid < 128)
    logits[(size_t)b * L_ + l0 + tid] = u_lds[0][tid] + u_lds[1][tid];
}

extern "C" void kernel_launch(void* const* d_in, const int* in_sizes, int n_in,
                              void* d_out, int out_size, void* d_ws, size_t ws_size,
                              hipStream_t stream) {
  const float* query = (const float*)d_in[0];
  const float* ref   = (const float*)d_in[1];
  const float* Wq    = (const float*)d_in[2];
  const float* bq    = (const float*)d_in[3];
  const float* Wr    = (const float*)d_in[4];
  const float* br    = (const float*)d_in[5];
  const float* v     = (const float*)d_in[6];

  float* e_out  = (float*)d_out;
  float* logits = e_out + (size_t)B_ * DIM * L_;  // 67108864

  char* ws = (char*)d_ws;
  u16*   Wrb = (u16*)ws;                // 512 KB
  float* q   = (float*)(ws + 524288);   // 128 KB

  prep_kernel<<<128, 256, 0, stream>>>(query, Wq, bq, Wr, q, Wrb);
  attn_main<<<dim3(16, 64), 512, 0, stream>>>(ref, Wrb, q, br, v, e_out, logits);
}